// Round 6
// baseline (299.416 us; speedup 1.0000x reference)
//
#include <hip/hip_runtime.h>
#include <hip/hip_bf16.h>

// Problem constants (B=2, P=2048, D=768, H=12, hd=64)
#define B_  2
#define P_  2048
#define D_  768
#define H_  12
#define HD_ 64
#define M_  (B_ * P_)   // 4096
#define N1_ (3 * D_)    // 2304

typedef __attribute__((ext_vector_type(8))) short short8;   // 8 bf16 (4 VGPRs)
typedef __attribute__((ext_vector_type(4))) float f32x4;    // MFMA accumulator
typedef unsigned short ushort;

__device__ __forceinline__ ushort f2bf(float f) {
    unsigned u = __float_as_uint(f);
    u += 0x7fffu + ((u >> 16) & 1u);   // RNE
    return (ushort)(u >> 16);
}

// ===========================================================================
// Kernel 1: qkv = x @ W_qkv (bf16 MFMA), fused per-head QK-LayerNorm epilogue,
// bf16 output scattered into [3][B][H][P][hd].  (unchanged from R5)
// ===========================================================================
__global__ __launch_bounds__(256) void gemm_qkv_mfma(
        const float* __restrict__ x, const float* __restrict__ w,
        const float* __restrict__ qs, const float* __restrict__ qb,
        const float* __restrict__ ks, const float* __restrict__ kb,
        ushort* __restrict__ qkv) {
    __shared__ __align__(16) ushort As[128][40];
    __shared__ __align__(16) ushort Bs[128][40];

    const int tid  = threadIdx.x;
    const int lane = tid & 63;
    const int wv   = tid >> 6;
    const int quad = lane >> 4;
    const int col  = lane & 15;
    const int wr   = (wv >> 1) * 64;
    const int wc   = (wv & 1) * 64;
    const int rowBase = blockIdx.y * 128;
    const int colBase = blockIdx.x * 128;

    const int nB    = tid & 127;
    const int khalf = tid >> 7;

    f32x4 acc[4][4];
#pragma unroll
    for (int i = 0; i < 4; i++)
#pragma unroll
        for (int j = 0; j < 4; j++) acc[i][j] = (f32x4){0.f, 0.f, 0.f, 0.f};

    for (int kt = 0; kt < D_ / 32; kt++) {
        const int k0 = kt * 32;
#pragma unroll
        for (int i = 0; i < 4; i++) {
            int e = tid + i * 256;
            int m = e >> 3, c4 = e & 7;
            float4 v = *(const float4*)(x + (size_t)(rowBase + m) * D_ + k0 + c4 * 4);
            ushort u4[4] = {f2bf(v.x), f2bf(v.y), f2bf(v.z), f2bf(v.w)};
            *(uint2*)&As[m][c4 * 4] = *(uint2*)u4;
        }
        {
            float bv[16];
#pragma unroll
            for (int j = 0; j < 16; j++)
                bv[j] = w[(size_t)(k0 + khalf * 16 + j) * N1_ + colBase + nB];
            ushort us[16];
#pragma unroll
            for (int j = 0; j < 16; j++) us[j] = f2bf(bv[j]);
            *(short8*)&Bs[nB][khalf * 16]     = *(short8*)&us[0];
            *(short8*)&Bs[nB][khalf * 16 + 8] = *(short8*)&us[8];
        }
        __syncthreads();
        short8 af[4], bf[4];
#pragma unroll
        for (int mt = 0; mt < 4; mt++) af[mt] = *(const short8*)&As[wr + mt * 16 + col][quad * 8];
#pragma unroll
        for (int nt = 0; nt < 4; nt++) bf[nt] = *(const short8*)&Bs[wc + nt * 16 + col][quad * 8];
#pragma unroll
        for (int mt = 0; mt < 4; mt++)
#pragma unroll
            for (int nt = 0; nt < 4; nt++)
                acc[mt][nt] = __builtin_amdgcn_mfma_f32_16x16x32_bf16(af[mt], bf[nt], acc[mt][nt], 0, 0, 0);
        __syncthreads();
    }

    const int comp = colBase / D_;
    const int rem  = colBase + wc - comp * D_;
    const int h    = rem >> 6;
    float sc4[4] = {0, 0, 0, 0}, bi4[4] = {0, 0, 0, 0};
    if (comp == 0) {
#pragma unroll
        for (int nt = 0; nt < 4; nt++) { sc4[nt] = qs[nt * 16 + col]; bi4[nt] = qb[nt * 16 + col]; }
    } else if (comp == 1) {
#pragma unroll
        for (int nt = 0; nt < 4; nt++) { sc4[nt] = ks[nt * 16 + col]; bi4[nt] = kb[nt * 16 + col]; }
    }

#pragma unroll
    for (int mt = 0; mt < 4; mt++) {
#pragma unroll
        for (int r = 0; r < 4; r++) {
            int m  = rowBase + wr + mt * 16 + quad * 4 + r;
            int bb = m >> 11;
            int p  = m & 2047;
            float v0 = acc[mt][0][r], v1 = acc[mt][1][r], v2 = acc[mt][2][r], v3 = acc[mt][3][r];
            if (comp < 2) {
                float s = v0 + v1 + v2 + v3;
#pragma unroll
                for (int off = 1; off < 16; off <<= 1) s += __shfl_xor(s, off, 64);
                float mean = s * (1.0f / 64.0f);
                float d0 = v0 - mean, d1 = v1 - mean, d2 = v2 - mean, d3 = v3 - mean;
                float sq = d0 * d0 + d1 * d1 + d2 * d2 + d3 * d3;
#pragma unroll
                for (int off = 1; off < 16; off <<= 1) sq += __shfl_xor(sq, off, 64);
                float inv = rsqrtf(sq * (1.0f / 64.0f) + 1e-6f);
                v0 = d0 * inv * sc4[0] + bi4[0];
                v1 = d1 * inv * sc4[1] + bi4[1];
                v2 = d2 * inv * sc4[2] + bi4[2];
                v3 = d3 * inv * sc4[3] + bi4[3];
                if (comp == 0) { v0 *= 0.125f; v1 *= 0.125f; v2 *= 0.125f; v3 *= 0.125f; }
            }
            size_t base = ((((size_t)comp * B_ + bb) * H_ + h) * P_ + p) * HD_;
            qkv[base +  0 + col] = f2bf(v0);
            qkv[base + 16 + col] = f2bf(v1);
            qkv[base + 32 + col] = f2bf(v2);
            qkv[base + 48 + col] = f2bf(v3);
        }
    }
}

// ===========================================================================
// Kernel 2: flash attention, bf16 MFMA, TRANSPOSED score layout.
// S^T = K·Q^T  (A = K rows from Ks, B = Q rows from Qs read as B-fragments).
// C-layout of S^T: row = key local = quad*4+reg, col = q local = lane&15
//   -> each lane holds 16 scores, all for ONE q; 4 consecutive keys per mt.
// Softmax: per-lane m/l state; cross-quad reduce = 2 shuffles.
// P stored to per-wave Ps[q][key] with packed b64 writes (4 per tile).
// O^T = V^T·P^T: A from Vs (transposed V), B from Ps, C col = q -> per-lane
// alpha rescale and 1/l, float4 writeback.
// ===========================================================================
__global__ __launch_bounds__(256) void attn_mfma(const ushort* __restrict__ qkv,
                                                 float* __restrict__ attn_s) {
    const int p0 = blockIdx.x * 64;
    const int bh = blockIdx.y;
    const int b  = bh / H_, h = bh % H_;
    const int tid  = threadIdx.x;
    const int lane = tid & 63;
    const int wv   = tid >> 6;
    const int quad = lane >> 4;
    const int col  = lane & 15;

    __shared__ __align__(16) ushort Qs[64][72];      // [q][dim]
    __shared__ __align__(16) ushort Ks[64][72];      // [key][dim]
    __shared__ __align__(16) ushort Vs[64][72];      // [dim][key] (transposed)
    __shared__ __align__(16) ushort Ps[4][16][72];   // per-wave [q][key]

    const size_t hs = (size_t)P_ * HD_;
    const ushort* qg = qkv + ((size_t)(0 * B_ + b) * H_ + h) * hs + (size_t)p0 * HD_;
    const ushort* kg = qkv + ((size_t)(1 * B_ + b) * H_ + h) * hs;
    const ushort* vg = qkv + ((size_t)(2 * B_ + b) * H_ + h) * hs;

    // Stage Q (64x64 bf16)
#pragma unroll
    for (int i = 0; i < 2; i++) {
        int e = tid + i * 256;
        int r = e >> 3, c8 = e & 7;
        *(uint4*)&Qs[r][c8 * 8] = *(const uint4*)(qg + (size_t)r * HD_ + c8 * 8);
    }
    __syncthreads();
    // Q as B-fragment: B[k=dim=quad*8+j][n=q=col] = Q[wv*16+col][ks*32+quad*8+j]
    short8 bq0 = *(const short8*)&Qs[wv * 16 + col][0 * 32 + quad * 8];
    short8 bq1 = *(const short8*)&Qs[wv * 16 + col][1 * 32 + quad * 8];

    float m_i = -1e30f;      // per-lane: q = p0 + wv*16 + col
    float l_i = 0.f;
    f32x4 oacc[4];           // O^T: [mt] -> dim mt*16+quad*4+reg, q = col
#pragma unroll
    for (int mt = 0; mt < 4; mt++) oacc[mt] = (f32x4){0.f, 0.f, 0.f, 0.f};

    const int vd = tid & 63, vkh = tid >> 6;

    for (int kt = 0; kt < P_ / 64; kt++) {
        __syncthreads();
        const ushort* kg_t = kg + (size_t)kt * 64 * HD_;
        const ushort* vg_t = vg + (size_t)kt * 64 * HD_;
#pragma unroll
        for (int i = 0; i < 2; i++) {
            int e = tid + i * 256;
            int r = e >> 3, c8 = e & 7;
            *(uint4*)&Ks[r][c8 * 8] = *(const uint4*)(kg_t + (size_t)r * HD_ + c8 * 8);
        }
        {
            ushort us[16];
#pragma unroll
            for (int j = 0; j < 16; j++)
                us[j] = vg_t[(size_t)(vkh * 16 + j) * HD_ + vd];
            *(short8*)&Vs[vd][vkh * 16]     = *(short8*)&us[0];
            *(short8*)&Vs[vd][vkh * 16 + 8] = *(short8*)&us[8];
        }
        __syncthreads();

        // S^T = K @ Q^T : s[mt] covers keys mt*16..+15 (rows), q = col
        f32x4 s[4];
#pragma unroll
        for (int mt = 0; mt < 4; mt++) s[mt] = (f32x4){0.f, 0.f, 0.f, 0.f};
#pragma unroll
        for (int mt = 0; mt < 4; mt++) {
            short8 a0 = *(const short8*)&Ks[mt * 16 + col][0 * 32 + quad * 8];
            short8 a1 = *(const short8*)&Ks[mt * 16 + col][1 * 32 + quad * 8];
            s[mt] = __builtin_amdgcn_mfma_f32_16x16x32_bf16(a0, bq0, s[mt], 0, 0, 0);
            s[mt] = __builtin_amdgcn_mfma_f32_16x16x32_bf16(a1, bq1, s[mt], 0, 0, 0);
        }

        // Online softmax: all 16 per-lane values belong to q = col.
        float tmax = s[0][0];
#pragma unroll
        for (int mt = 0; mt < 4; mt++)
#pragma unroll
            for (int r = 0; r < 4; r++) tmax = fmaxf(tmax, s[mt][r]);
        tmax = fmaxf(tmax, __shfl_xor(tmax, 16, 64));
        tmax = fmaxf(tmax, __shfl_xor(tmax, 32, 64));
        float mnew  = fmaxf(m_i, tmax);
        float alpha = __expf(m_i - mnew);
        m_i = mnew;
        float rs = 0.f;
#pragma unroll
        for (int mt = 0; mt < 4; mt++) {
            ushort pk[4];
#pragma unroll
            for (int r = 0; r < 4; r++) {
                float p = __expf(s[mt][r] - mnew);
                rs += p;
                pk[r] = f2bf(p);
            }
            // keys mt*16 + quad*4 + (0..3): one b64 packed write
            *(uint2*)&Ps[wv][col][mt * 16 + quad * 4] = *(uint2*)pk;
        }
        rs += __shfl_xor(rs, 16, 64);
        rs += __shfl_xor(rs, 32, 64);
        l_i = l_i * alpha + rs;
#pragma unroll
        for (int mt = 0; mt < 4; mt++)
#pragma unroll
            for (int r = 0; r < 4; r++) oacc[mt][r] *= alpha;

        // O^T += V^T @ P^T  (Ps is per-wave; DS ops in-order within wave -> no barrier)
#pragma unroll
        for (int ks2 = 0; ks2 < 2; ks2++) {
            short8 bp = *(const short8*)&Ps[wv][col][ks2 * 32 + quad * 8];
#pragma unroll
            for (int mt = 0; mt < 4; mt++) {
                short8 av = *(const short8*)&Vs[mt * 16 + col][ks2 * 32 + quad * 8];
                oacc[mt] = __builtin_amdgcn_mfma_f32_16x16x32_bf16(av, bp, oacc[mt], 0, 0, 0);
            }
        }
    }

    // Writeback: lane's q = p0 + wv*16 + col; dims mt*16+quad*4+(0..3) -> float4
    {
        float invl = 1.0f / l_i;
        float* dst = attn_s + (size_t)(b * P_ + p0 + wv * 16 + col) * D_ + h * HD_;
#pragma unroll
        for (int mt = 0; mt < 4; mt++) {
            float4 o4 = {oacc[mt][0] * invl, oacc[mt][1] * invl,
                         oacc[mt][2] * invl, oacc[mt][3] * invl};
            *(float4*)(dst + mt * 16 + quad * 4) = o4;
        }
    }
}

// ===========================================================================
// Kernel 3: LayerNorm over D=768. fp32 in (d_out scratch), bf16 out (ln_buf).
// ===========================================================================
__global__ __launch_bounds__(256) void ln_o(const float* __restrict__ a,
                                            ushort* __restrict__ lnb,
                                            const float* __restrict__ osc,
                                            const float* __restrict__ ob) {
    __shared__ float red[4];
    __shared__ float red2[4];
    const int row = blockIdx.x;
    const int tid = threadIdx.x;
    const size_t base = (size_t)row * D_;

    float v0 = a[base + tid];
    float v1 = a[base + tid + 256];
    float v2 = a[base + tid + 512];
    float s = v0 + v1 + v2;
#pragma unroll
    for (int o = 32; o > 0; o >>= 1) s += __shfl_xor(s, o, 64);
    if ((tid & 63) == 0) red[tid >> 6] = s;
    __syncthreads();
    float mean = (red[0] + red[1] + red[2] + red[3]) * (1.0f / 768.0f);
    float d0 = v0 - mean, d1 = v1 - mean, d2 = v2 - mean;
    float sq = d0 * d0 + d1 * d1 + d2 * d2;
#pragma unroll
    for (int o = 32; o > 0; o >>= 1) sq += __shfl_xor(sq, o, 64);
    if ((tid & 63) == 0) red2[tid >> 6] = sq;
    __syncthreads();
    float var = (red2[0] + red2[1] + red2[2] + red2[3]) * (1.0f / 768.0f);
    float inv = rsqrtf(var + 1e-6f);
    lnb[base + tid]       = f2bf(d0 * inv * osc[tid]       + ob[tid]);
    lnb[base + tid + 256] = f2bf(d1 * inv * osc[tid + 256] + ob[tid + 256]);
    lnb[base + tid + 512] = f2bf(d2 * inv * osc[tid + 512] + ob[tid + 512]);
}

// ===========================================================================
// Kernel 4: out = ln_buf(bf16) @ W_out + b_out, fp32 output.  (unchanged)
// ===========================================================================
__global__ __launch_bounds__(256) void gemm_out_mfma(
        const ushort* __restrict__ a, const float* __restrict__ w,
        const float* __restrict__ bias, float* __restrict__ out) {
    __shared__ __align__(16) ushort As[128][40];
    __shared__ __align__(16) ushort Bs[128][40];

    const int tid  = threadIdx.x;
    const int lane = tid & 63;
    const int wv   = tid >> 6;
    const int quad = lane >> 4;
    const int col  = lane & 15;
    const int wr   = (wv >> 1) * 64;
    const int wc   = (wv & 1) * 64;
    const int rowBase = blockIdx.y * 128;
    const int colBase = blockIdx.x * 128;

    const int nB    = tid & 127;
    const int khalf = tid >> 7;

    f32x4 acc[4][4];
#pragma unroll
    for (int i = 0; i < 4; i++)
#pragma unroll
        for (int j = 0; j < 4; j++) acc[i][j] = (f32x4){0.f, 0.f, 0.f, 0.f};

    for (int kt = 0; kt < D_ / 32; kt++) {
        const int k0 = kt * 32;
#pragma unroll
        for (int i = 0; i < 2; i++) {
            int e = tid + i * 256;
            int m = e >> 2, c8 = e & 3;
            *(uint4*)&As[m][c8 * 8] = *(const uint4*)(a + (size_t)(rowBase + m) * D_ + k0 + c8 * 8);
        }
        {
            float bv[16];
#pragma unroll
            for (int j = 0; j < 16; j++)
                bv[j] = w[(size_t)(k0 + khalf * 16 + j) * D_ + colBase + nB];
            ushort us[16];
#pragma unroll
            for (int j = 0; j < 16; j++) us[j] = f2bf(bv[j]);
            *(short8*)&Bs[nB][khalf * 16]     = *(short8*)&us[0];
            *(short8*)&Bs[nB][khalf * 16 + 8] = *(short8*)&us[8];
        }
        __syncthreads();
        short8 af[4], bf[4];
#pragma unroll
        for (int mt = 0; mt < 4; mt++) af[mt] = *(const short8*)&As[wr + mt * 16 + col][quad * 8];
#pragma unroll
        for (int nt = 0; nt < 4; nt++) bf[nt] = *(const short8*)&Bs[wc + nt * 16 + col][quad * 8];
#pragma unroll
        for (int mt = 0; mt < 4; mt++)
#pragma unroll
            for (int nt = 0; nt < 4; nt++)
                acc[mt][nt] = __builtin_amdgcn_mfma_f32_16x16x32_bf16(af[mt], bf[nt], acc[mt][nt], 0, 0, 0);
        __syncthreads();
    }

    float b4[4];
#pragma unroll
    for (int nt = 0; nt < 4; nt++) b4[nt] = bias[colBase + wc + nt * 16 + col];
#pragma unroll
    for (int mt = 0; mt < 4; mt++) {
#pragma unroll
        for (int r = 0; r < 4; r++) {
            int m = rowBase + wr + mt * 16 + quad * 4 + r;
            float* dst = out + (size_t)m * D_ + colBase + wc;
#pragma unroll
            for (int nt = 0; nt < 4; nt++)
                dst[nt * 16 + col] = acc[mt][nt][r] + b4[nt];
        }
    }
}

// ---------------------------------------------------------------------------
extern "C" void kernel_launch(void* const* d_in, const int* in_sizes, int n_in,
                              void* d_out, int out_size, void* d_ws, size_t ws_size,
                              hipStream_t stream) {
    const float* x    = (const float*)d_in[0];
    const float* Wqkv = (const float*)d_in[1];
    const float* qs   = (const float*)d_in[2];
    const float* qb   = (const float*)d_in[3];
    const float* ks   = (const float*)d_in[4];
    const float* kb   = (const float*)d_in[5];
    const float* osc  = (const float*)d_in[6];
    const float* ob   = (const float*)d_in[7];
    const float* Wout = (const float*)d_in[8];
    const float* bout = (const float*)d_in[9];
    float* out = (float*)d_out;

    ushort* qkv    = (ushort*)d_ws;   // [3][B][H][P][hd] bf16, 18.9 MB
    float*  attn_s = out;             // d_out doubles as attention-output scratch
    ushort* ln_buf = qkv;             // overlays dead q-region after attn

    gemm_qkv_mfma<<<dim3(N1_ / 128, M_ / 128), 256, 0, stream>>>(x, Wqkv, qs, qb, ks, kb, qkv);
    attn_mfma<<<dim3(P_ / 64, B_ * H_), 256, 0, stream>>>(qkv, attn_s);
    ln_o<<<dim3(M_), 256, 0, stream>>>(attn_s, ln_buf, osc, ob);
    gemm_out_mfma<<<dim3(D_ / 128, M_ / 128), 256, 0, stream>>>(ln_buf, Wout, bout, out);
}

// Round 7
// 272.761 us; speedup vs baseline: 1.0977x; 1.0977x over previous
//
#include <hip/hip_runtime.h>
#include <hip/hip_bf16.h>

// Problem constants (B=2, P=2048, D=768, H=12, hd=64)
#define B_  2
#define P_  2048
#define D_  768
#define H_  12
#define HD_ 64
#define M_  (B_ * P_)   // 4096
#define N1_ (3 * D_)    // 2304

typedef __attribute__((ext_vector_type(8))) short short8;   // 8 bf16 (4 VGPRs)
typedef __attribute__((ext_vector_type(4))) float f32x4;    // MFMA accumulator
typedef unsigned short ushort;

__device__ __forceinline__ ushort f2bf(float f) {
    unsigned u = __float_as_uint(f);
    u += 0x7fffu + ((u >> 16) & 1u);   // RNE
    return (ushort)(u >> 16);
}

// ===========================================================================
// Kernel 1: qkv = x @ W_qkv (bf16 MFMA) + fused per-head QK-LayerNorm.
// R5 structure + register-prefetch software pipeline (loads for k-tile t+1
// issued during compute of tile t; vmcnt drains at next LDS-store).
// ===========================================================================
__global__ __launch_bounds__(256) void gemm_qkv_mfma(
        const float* __restrict__ x, const float* __restrict__ w,
        const float* __restrict__ qs, const float* __restrict__ qb,
        const float* __restrict__ ks, const float* __restrict__ kb,
        ushort* __restrict__ qkv) {
    __shared__ __align__(16) ushort As[128][40];
    __shared__ __align__(16) ushort Bs[128][40];

    const int tid  = threadIdx.x;
    const int lane = tid & 63;
    const int wv   = tid >> 6;
    const int quad = lane >> 4;
    const int col  = lane & 15;
    const int wr   = (wv >> 1) * 64;
    const int wc   = (wv & 1) * 64;
    const int rowBase = blockIdx.y * 128;
    const int colBase = blockIdx.x * 128;

    const int nB    = tid & 127;
    const int khalf = tid >> 7;
    const int am    = tid >> 3, ac4 = tid & 7;   // A staging coords (i-th chunk adds 32 rows)

    float4 apre[4];
    float  bpre[16];

    auto load_tile = [&](int kt) {
        const int k0 = kt * 32;
#pragma unroll
        for (int i = 0; i < 4; i++)
            apre[i] = *(const float4*)(x + (size_t)(rowBase + am + i * 32) * D_ + k0 + ac4 * 4);
#pragma unroll
        for (int j = 0; j < 16; j++)
            bpre[j] = w[(size_t)(k0 + khalf * 16 + j) * N1_ + colBase + nB];
    };

    f32x4 acc[4][4];
#pragma unroll
    for (int i = 0; i < 4; i++)
#pragma unroll
        for (int j = 0; j < 4; j++) acc[i][j] = (f32x4){0.f, 0.f, 0.f, 0.f};

    load_tile(0);
    const int NT = D_ / 32;
    for (int kt = 0; kt < NT; kt++) {
        __syncthreads();   // previous tile's LDS reads complete
#pragma unroll
        for (int i = 0; i < 4; i++) {
            ushort u4[4] = {f2bf(apre[i].x), f2bf(apre[i].y), f2bf(apre[i].z), f2bf(apre[i].w)};
            *(uint2*)&As[am + i * 32][ac4 * 4] = *(uint2*)u4;
        }
        {
            ushort us[16];
#pragma unroll
            for (int j = 0; j < 16; j++) us[j] = f2bf(bpre[j]);
            *(short8*)&Bs[nB][khalf * 16]     = *(short8*)&us[0];
            *(short8*)&Bs[nB][khalf * 16 + 8] = *(short8*)&us[8];
        }
        __syncthreads();
        if (kt + 1 < NT) load_tile(kt + 1);

        short8 af[4], bf[4];
#pragma unroll
        for (int mt = 0; mt < 4; mt++) af[mt] = *(const short8*)&As[wr + mt * 16 + col][quad * 8];
#pragma unroll
        for (int nt = 0; nt < 4; nt++) bf[nt] = *(const short8*)&Bs[wc + nt * 16 + col][quad * 8];
#pragma unroll
        for (int mt = 0; mt < 4; mt++)
#pragma unroll
            for (int nt = 0; nt < 4; nt++)
                acc[mt][nt] = __builtin_amdgcn_mfma_f32_16x16x32_bf16(af[mt], bf[nt], acc[mt][nt], 0, 0, 0);
    }

    const int comp = colBase / D_;
    const int rem  = colBase + wc - comp * D_;
    const int h    = rem >> 6;
    float sc4[4] = {0, 0, 0, 0}, bi4[4] = {0, 0, 0, 0};
    if (comp == 0) {
#pragma unroll
        for (int nt = 0; nt < 4; nt++) { sc4[nt] = qs[nt * 16 + col]; bi4[nt] = qb[nt * 16 + col]; }
    } else if (comp == 1) {
#pragma unroll
        for (int nt = 0; nt < 4; nt++) { sc4[nt] = ks[nt * 16 + col]; bi4[nt] = kb[nt * 16 + col]; }
    }

#pragma unroll
    for (int mt = 0; mt < 4; mt++) {
#pragma unroll
        for (int r = 0; r < 4; r++) {
            int m  = rowBase + wr + mt * 16 + quad * 4 + r;
            int bb = m >> 11;
            int p  = m & 2047;
            float v0 = acc[mt][0][r], v1 = acc[mt][1][r], v2 = acc[mt][2][r], v3 = acc[mt][3][r];
            if (comp < 2) {
                float s = v0 + v1 + v2 + v3;
#pragma unroll
                for (int off = 1; off < 16; off <<= 1) s += __shfl_xor(s, off, 64);
                float mean = s * (1.0f / 64.0f);
                float d0 = v0 - mean, d1 = v1 - mean, d2 = v2 - mean, d3 = v3 - mean;
                float sq = d0 * d0 + d1 * d1 + d2 * d2 + d3 * d3;
#pragma unroll
                for (int off = 1; off < 16; off <<= 1) sq += __shfl_xor(sq, off, 64);
                float inv = rsqrtf(sq * (1.0f / 64.0f) + 1e-6f);
                v0 = d0 * inv * sc4[0] + bi4[0];
                v1 = d1 * inv * sc4[1] + bi4[1];
                v2 = d2 * inv * sc4[2] + bi4[2];
                v3 = d3 * inv * sc4[3] + bi4[3];
                if (comp == 0) { v0 *= 0.125f; v1 *= 0.125f; v2 *= 0.125f; v3 *= 0.125f; }
            }
            size_t base = ((((size_t)comp * B_ + bb) * H_ + h) * P_ + p) * HD_;
            qkv[base +  0 + col] = f2bf(v0);
            qkv[base + 16 + col] = f2bf(v1);
            qkv[base + 32 + col] = f2bf(v2);
            qkv[base + 48 + col] = f2bf(v3);
        }
    }
}

// ===========================================================================
// Kernel 2: flash attention, bf16 MFMA 16x16x32 — R5 layout (S = Q·K^T)
// verbatim, plus register-prefetch pipeline for the K/V tile loads.
// ===========================================================================
__global__ __launch_bounds__(256) void attn_mfma(const ushort* __restrict__ qkv,
                                                 float* __restrict__ attn_s) {
    const int p0 = blockIdx.x * 64;
    const int bh = blockIdx.y;
    const int b  = bh / H_, h = bh % H_;
    const int tid  = threadIdx.x;
    const int lane = tid & 63;
    const int wv   = tid >> 6;
    const int quad = lane >> 4;
    const int col  = lane & 15;

    __shared__ __align__(16) ushort Qs[64][72];
    __shared__ __align__(16) ushort Ks[64][72];
    __shared__ __align__(16) ushort Vs[64][72];      // [dim][key] transposed
    __shared__ __align__(16) ushort Ps[4][16][72];

    const size_t hs = (size_t)P_ * HD_;
    const ushort* qg = qkv + ((size_t)(0 * B_ + b) * H_ + h) * hs + (size_t)p0 * HD_;
    const ushort* kg = qkv + ((size_t)(1 * B_ + b) * H_ + h) * hs;
    const ushort* vg = qkv + ((size_t)(2 * B_ + b) * H_ + h) * hs;

    // Stage Q (64x64 bf16)
#pragma unroll
    for (int i = 0; i < 2; i++) {
        int e = tid + i * 256;
        int r = e >> 3, c8 = e & 7;
        *(uint4*)&Qs[r][c8 * 8] = *(const uint4*)(qg + (size_t)r * HD_ + c8 * 8);
    }
    __syncthreads();
    short8 aq0 = *(const short8*)&Qs[wv * 16 + col][0 * 32 + quad * 8];
    short8 aq1 = *(const short8*)&Qs[wv * 16 + col][1 * 32 + quad * 8];

    float m_i[4] = {-1e30f, -1e30f, -1e30f, -1e30f};
    float l_i[4] = {0.f, 0.f, 0.f, 0.f};
    f32x4 oacc[4];
#pragma unroll
    for (int nt = 0; nt < 4; nt++) oacc[nt] = (f32x4){0.f, 0.f, 0.f, 0.f};

    const int kr = tid >> 3, kc8 = tid & 7;    // K staging coords (chunk i adds 32 rows)
    const int vd = tid & 63,  vkh = tid >> 6;  // V staging coords

    uint4  kpre[2];
    ushort vpre[16];
    auto load_tile = [&](int kt) {
        const ushort* kg_t = kg + (size_t)kt * 64 * HD_;
        const ushort* vg_t = vg + (size_t)kt * 64 * HD_;
        kpre[0] = *(const uint4*)(kg_t + (size_t)kr * HD_ + kc8 * 8);
        kpre[1] = *(const uint4*)(kg_t + (size_t)(kr + 32) * HD_ + kc8 * 8);
#pragma unroll
        for (int j = 0; j < 16; j++)
            vpre[j] = vg_t[(size_t)(vkh * 16 + j) * HD_ + vd];
    };

    load_tile(0);
    const int NT = P_ / 64;
    for (int kt = 0; kt < NT; kt++) {
        __syncthreads();   // previous tile's Ks/Vs reads done
        *(uint4*)&Ks[kr][kc8 * 8]      = kpre[0];
        *(uint4*)&Ks[kr + 32][kc8 * 8] = kpre[1];
        *(short8*)&Vs[vd][vkh * 16]     = *(short8*)&vpre[0];
        *(short8*)&Vs[vd][vkh * 16 + 8] = *(short8*)&vpre[8];
        __syncthreads();
        if (kt + 1 < NT) load_tile(kt + 1);

        // S = Q @ K^T
        f32x4 s[4];
#pragma unroll
        for (int nt = 0; nt < 4; nt++) {
            s[nt] = (f32x4){0.f, 0.f, 0.f, 0.f};
            short8 b0 = *(const short8*)&Ks[nt * 16 + col][0 * 32 + quad * 8];
            short8 b1 = *(const short8*)&Ks[nt * 16 + col][1 * 32 + quad * 8];
            s[nt] = __builtin_amdgcn_mfma_f32_16x16x32_bf16(aq0, b0, s[nt], 0, 0, 0);
            s[nt] = __builtin_amdgcn_mfma_f32_16x16x32_bf16(aq1, b1, s[nt], 0, 0, 0);
        }

        // Online softmax per row (row = quad*4+r)
#pragma unroll
        for (int r = 0; r < 4; r++) {
            float mt = fmaxf(fmaxf(s[0][r], s[1][r]), fmaxf(s[2][r], s[3][r]));
#pragma unroll
            for (int off = 1; off < 16; off <<= 1) mt = fmaxf(mt, __shfl_xor(mt, off, 64));
            float mnew = fmaxf(m_i[r], mt);
            float alpha = __expf(m_i[r] - mnew);
            float rs = 0.f;
#pragma unroll
            for (int nt = 0; nt < 4; nt++) {
                float p = __expf(s[nt][r] - mnew);
                rs += p;
                Ps[wv][quad * 4 + r][nt * 16 + col] = f2bf(p);
            }
#pragma unroll
            for (int off = 1; off < 16; off <<= 1) rs += __shfl_xor(rs, off, 64);
            l_i[r] = l_i[r] * alpha + rs;
            m_i[r] = mnew;
#pragma unroll
            for (int nt = 0; nt < 4; nt++) oacc[nt][r] *= alpha;
        }
        __syncthreads();

        // O += P @ V
#pragma unroll
        for (int nt = 0; nt < 4; nt++) {
#pragma unroll
            for (int ks2 = 0; ks2 < 2; ks2++) {
                short8 a   = *(const short8*)&Ps[wv][col][ks2 * 32 + quad * 8];
                short8 bfr = *(const short8*)&Vs[nt * 16 + col][ks2 * 32 + quad * 8];
                oacc[nt] = __builtin_amdgcn_mfma_f32_16x16x32_bf16(a, bfr, oacc[nt], 0, 0, 0);
            }
        }
    }

#pragma unroll
    for (int r = 0; r < 4; r++) {
        float invl = 1.0f / l_i[r];
        int q = p0 + wv * 16 + quad * 4 + r;
        float* dst = attn_s + (size_t)(b * P_ + q) * D_ + h * HD_;
#pragma unroll
        for (int nt = 0; nt < 4; nt++) dst[nt * 16 + col] = oacc[nt][r] * invl;
    }
}

// ===========================================================================
// Kernel 3: LayerNorm over D=768. fp32 in (d_out scratch), bf16 out (ln_buf).
// ===========================================================================
__global__ __launch_bounds__(256) void ln_o(const float* __restrict__ a,
                                            ushort* __restrict__ lnb,
                                            const float* __restrict__ osc,
                                            const float* __restrict__ ob) {
    __shared__ float red[4];
    __shared__ float red2[4];
    const int row = blockIdx.x;
    const int tid = threadIdx.x;
    const size_t base = (size_t)row * D_;

    float v0 = a[base + tid];
    float v1 = a[base + tid + 256];
    float v2 = a[base + tid + 512];
    float s = v0 + v1 + v2;
#pragma unroll
    for (int o = 32; o > 0; o >>= 1) s += __shfl_xor(s, o, 64);
    if ((tid & 63) == 0) red[tid >> 6] = s;
    __syncthreads();
    float mean = (red[0] + red[1] + red[2] + red[3]) * (1.0f / 768.0f);
    float d0 = v0 - mean, d1 = v1 - mean, d2 = v2 - mean;
    float sq = d0 * d0 + d1 * d1 + d2 * d2;
#pragma unroll
    for (int o = 32; o > 0; o >>= 1) sq += __shfl_xor(sq, o, 64);
    if ((tid & 63) == 0) red2[tid >> 6] = sq;
    __syncthreads();
    float var = (red2[0] + red2[1] + red2[2] + red2[3]) * (1.0f / 768.0f);
    float inv = rsqrtf(var + 1e-6f);
    lnb[base + tid]       = f2bf(d0 * inv * osc[tid]       + ob[tid]);
    lnb[base + tid + 256] = f2bf(d1 * inv * osc[tid + 256] + ob[tid + 256]);
    lnb[base + tid + 512] = f2bf(d2 * inv * osc[tid + 512] + ob[tid + 512]);
}

// ===========================================================================
// Kernel 4: out = ln_buf(bf16) @ W_out + b_out, fp32 output.
// R5 structure + register-prefetch pipeline.
// ===========================================================================
__global__ __launch_bounds__(256) void gemm_out_mfma(
        const ushort* __restrict__ a, const float* __restrict__ w,
        const float* __restrict__ bias, float* __restrict__ out) {
    __shared__ __align__(16) ushort As[128][40];
    __shared__ __align__(16) ushort Bs[128][40];

    const int tid  = threadIdx.x;
    const int lane = tid & 63;
    const int wv   = tid >> 6;
    const int quad = lane >> 4;
    const int col  = lane & 15;
    const int wr   = (wv >> 1) * 64;
    const int wc   = (wv & 1) * 64;
    const int rowBase = blockIdx.y * 128;
    const int colBase = blockIdx.x * 128;

    const int nB    = tid & 127;
    const int khalf = tid >> 7;
    const int am    = tid >> 2, ac8 = tid & 3;   // A staging (chunk i adds 64 rows)

    uint4 apre[2];
    float bpre[16];
    auto load_tile = [&](int kt) {
        const int k0 = kt * 32;
        apre[0] = *(const uint4*)(a + (size_t)(rowBase + am) * D_ + k0 + ac8 * 8);
        apre[1] = *(const uint4*)(a + (size_t)(rowBase + am + 64) * D_ + k0 + ac8 * 8);
#pragma unroll
        for (int j = 0; j < 16; j++)
            bpre[j] = w[(size_t)(k0 + khalf * 16 + j) * D_ + colBase + nB];
    };

    f32x4 acc[4][4];
#pragma unroll
    for (int i = 0; i < 4; i++)
#pragma unroll
        for (int j = 0; j < 4; j++) acc[i][j] = (f32x4){0.f, 0.f, 0.f, 0.f};

    load_tile(0);
    const int NT = D_ / 32;
    for (int kt = 0; kt < NT; kt++) {
        __syncthreads();
        *(uint4*)&As[am][ac8 * 8]      = apre[0];
        *(uint4*)&As[am + 64][ac8 * 8] = apre[1];
        {
            ushort us[16];
#pragma unroll
            for (int j = 0; j < 16; j++) us[j] = f2bf(bpre[j]);
            *(short8*)&Bs[nB][khalf * 16]     = *(short8*)&us[0];
            *(short8*)&Bs[nB][khalf * 16 + 8] = *(short8*)&us[8];
        }
        __syncthreads();
        if (kt + 1 < NT) load_tile(kt + 1);

        short8 af[4], bf[4];
#pragma unroll
        for (int mt = 0; mt < 4; mt++) af[mt] = *(const short8*)&As[wr + mt * 16 + col][quad * 8];
#pragma unroll
        for (int nt = 0; nt < 4; nt++) bf[nt] = *(const short8*)&Bs[wc + nt * 16 + col][quad * 8];
#pragma unroll
        for (int mt = 0; mt < 4; mt++)
#pragma unroll
            for (int nt = 0; nt < 4; nt++)
                acc[mt][nt] = __builtin_amdgcn_mfma_f32_16x16x32_bf16(af[mt], bf[nt], acc[mt][nt], 0, 0, 0);
    }

    float b4[4];
#pragma unroll
    for (int nt = 0; nt < 4; nt++) b4[nt] = bias[colBase + wc + nt * 16 + col];
#pragma unroll
    for (int mt = 0; mt < 4; mt++) {
#pragma unroll
        for (int r = 0; r < 4; r++) {
            int m = rowBase + wr + mt * 16 + quad * 4 + r;
            float* dst = out + (size_t)m * D_ + colBase + wc;
#pragma unroll
            for (int nt = 0; nt < 4; nt++)
                dst[nt * 16 + col] = acc[mt][nt][r] + b4[nt];
        }
    }
}

// ---------------------------------------------------------------------------
extern "C" void kernel_launch(void* const* d_in, const int* in_sizes, int n_in,
                              void* d_out, int out_size, void* d_ws, size_t ws_size,
                              hipStream_t stream) {
    const float* x    = (const float*)d_in[0];
    const float* Wqkv = (const float*)d_in[1];
    const float* qs   = (const float*)d_in[2];
    const float* qb   = (const float*)d_in[3];
    const float* ks   = (const float*)d_in[4];
    const float* kb   = (const float*)d_in[5];
    const float* osc  = (const float*)d_in[6];
    const float* ob   = (const float*)d_in[7];
    const float* Wout = (const float*)d_in[8];
    const float* bout = (const float*)d_in[9];
    float* out = (float*)d_out;

    ushort* qkv    = (ushort*)d_ws;   // [3][B][H][P][hd] bf16, 18.9 MB
    float*  attn_s = out;             // d_out doubles as attention-output scratch
    ushort* ln_buf = qkv;             // overlays dead q-region after attn

    gemm_qkv_mfma<<<dim3(N1_ / 128, M_ / 128), 256, 0, stream>>>(x, Wqkv, qs, qb, ks, kb, qkv);
    attn_mfma<<<dim3(P_ / 64, B_ * H_), 256, 0, stream>>>(qkv, attn_s);
    ln_o<<<dim3(M_), 256, 0, stream>>>(attn_s, ln_buf, osc, ob);
    gemm_out_mfma<<<dim3(D_ / 128, M_ / 128), 256, 0, stream>>>(ln_buf, Wout, bout, out);
}

// Round 8
// 267.650 us; speedup vs baseline: 1.1187x; 1.0191x over previous
//
#include <hip/hip_runtime.h>
#include <hip/hip_bf16.h>

// Problem constants (B=2, P=2048, D=768, H=12, hd=64)
#define B_  2
#define P_  2048
#define D_  768
#define H_  12
#define HD_ 64
#define M_  (B_ * P_)   // 4096
#define N1_ (3 * D_)    // 2304

typedef __attribute__((ext_vector_type(8))) short short8;   // 8 bf16 (4 VGPRs)
typedef __attribute__((ext_vector_type(4))) float f32x4;    // MFMA accumulator
typedef unsigned short ushort;

__device__ __forceinline__ ushort f2bf(float f) {
    unsigned u = __float_as_uint(f);
    u += 0x7fffu + ((u >> 16) & 1u);   // RNE
    return (ushort)(u >> 16);
}

// ===========================================================================
// Kernel 1: qkv = x @ W_qkv (bf16 MFMA) + fused per-head QK-LayerNorm.
// (unchanged from R7: register-prefetch pipeline)
// ===========================================================================
__global__ __launch_bounds__(256) void gemm_qkv_mfma(
        const float* __restrict__ x, const float* __restrict__ w,
        const float* __restrict__ qs, const float* __restrict__ qb,
        const float* __restrict__ ks, const float* __restrict__ kb,
        ushort* __restrict__ qkv) {
    __shared__ __align__(16) ushort As[128][40];
    __shared__ __align__(16) ushort Bs[128][40];

    const int tid  = threadIdx.x;
    const int lane = tid & 63;
    const int wv   = tid >> 6;
    const int quad = lane >> 4;
    const int col  = lane & 15;
    const int wr   = (wv >> 1) * 64;
    const int wc   = (wv & 1) * 64;
    const int rowBase = blockIdx.y * 128;
    const int colBase = blockIdx.x * 128;

    const int nB    = tid & 127;
    const int khalf = tid >> 7;
    const int am    = tid >> 3, ac4 = tid & 7;

    float4 apre[4];
    float  bpre[16];

    auto load_tile = [&](int kt) {
        const int k0 = kt * 32;
#pragma unroll
        for (int i = 0; i < 4; i++)
            apre[i] = *(const float4*)(x + (size_t)(rowBase + am + i * 32) * D_ + k0 + ac4 * 4);
#pragma unroll
        for (int j = 0; j < 16; j++)
            bpre[j] = w[(size_t)(k0 + khalf * 16 + j) * N1_ + colBase + nB];
    };

    f32x4 acc[4][4];
#pragma unroll
    for (int i = 0; i < 4; i++)
#pragma unroll
        for (int j = 0; j < 4; j++) acc[i][j] = (f32x4){0.f, 0.f, 0.f, 0.f};

    load_tile(0);
    const int NT = D_ / 32;
    for (int kt = 0; kt < NT; kt++) {
        __syncthreads();
#pragma unroll
        for (int i = 0; i < 4; i++) {
            ushort u4[4] = {f2bf(apre[i].x), f2bf(apre[i].y), f2bf(apre[i].z), f2bf(apre[i].w)};
            *(uint2*)&As[am + i * 32][ac4 * 4] = *(uint2*)u4;
        }
        {
            ushort us[16];
#pragma unroll
            for (int j = 0; j < 16; j++) us[j] = f2bf(bpre[j]);
            *(short8*)&Bs[nB][khalf * 16]     = *(short8*)&us[0];
            *(short8*)&Bs[nB][khalf * 16 + 8] = *(short8*)&us[8];
        }
        __syncthreads();
        if (kt + 1 < NT) load_tile(kt + 1);

        short8 af[4], bf[4];
#pragma unroll
        for (int mt = 0; mt < 4; mt++) af[mt] = *(const short8*)&As[wr + mt * 16 + col][quad * 8];
#pragma unroll
        for (int nt = 0; nt < 4; nt++) bf[nt] = *(const short8*)&Bs[wc + nt * 16 + col][quad * 8];
#pragma unroll
        for (int mt = 0; mt < 4; mt++)
#pragma unroll
            for (int nt = 0; nt < 4; nt++)
                acc[mt][nt] = __builtin_amdgcn_mfma_f32_16x16x32_bf16(af[mt], bf[nt], acc[mt][nt], 0, 0, 0);
    }

    const int comp = colBase / D_;
    const int rem  = colBase + wc - comp * D_;
    const int h    = rem >> 6;
    float sc4[4] = {0, 0, 0, 0}, bi4[4] = {0, 0, 0, 0};
    if (comp == 0) {
#pragma unroll
        for (int nt = 0; nt < 4; nt++) { sc4[nt] = qs[nt * 16 + col]; bi4[nt] = qb[nt * 16 + col]; }
    } else if (comp == 1) {
#pragma unroll
        for (int nt = 0; nt < 4; nt++) { sc4[nt] = ks[nt * 16 + col]; bi4[nt] = kb[nt * 16 + col]; }
    }

#pragma unroll
    for (int mt = 0; mt < 4; mt++) {
#pragma unroll
        for (int r = 0; r < 4; r++) {
            int m  = rowBase + wr + mt * 16 + quad * 4 + r;
            int bb = m >> 11;
            int p  = m & 2047;
            float v0 = acc[mt][0][r], v1 = acc[mt][1][r], v2 = acc[mt][2][r], v3 = acc[mt][3][r];
            if (comp < 2) {
                float s = v0 + v1 + v2 + v3;
#pragma unroll
                for (int off = 1; off < 16; off <<= 1) s += __shfl_xor(s, off, 64);
                float mean = s * (1.0f / 64.0f);
                float d0 = v0 - mean, d1 = v1 - mean, d2 = v2 - mean, d3 = v3 - mean;
                float sq = d0 * d0 + d1 * d1 + d2 * d2 + d3 * d3;
#pragma unroll
                for (int off = 1; off < 16; off <<= 1) sq += __shfl_xor(sq, off, 64);
                float inv = rsqrtf(sq * (1.0f / 64.0f) + 1e-6f);
                v0 = d0 * inv * sc4[0] + bi4[0];
                v1 = d1 * inv * sc4[1] + bi4[1];
                v2 = d2 * inv * sc4[2] + bi4[2];
                v3 = d3 * inv * sc4[3] + bi4[3];
                if (comp == 0) { v0 *= 0.125f; v1 *= 0.125f; v2 *= 0.125f; v3 *= 0.125f; }
            }
            size_t base = ((((size_t)comp * B_ + bb) * H_ + h) * P_ + p) * HD_;
            qkv[base +  0 + col] = f2bf(v0);
            qkv[base + 16 + col] = f2bf(v1);
            qkv[base + 32 + col] = f2bf(v2);
            qkv[base + 48 + col] = f2bf(v3);
        }
    }
}

// ===========================================================================
// Kernel 2: flash attention, bf16 MFMA 16x16x32, R7 structure, but with
// UNNORMALIZED clamped softmax: scores are bounded (q,k are LayerNormed,
// q scaled by 0.125 -> s ~ N(0,1)); p = exp(min(s,60)) cannot overflow
// (2048*e^60 ~ 2e29 << fp32 max). No running max, no alpha rescale, no
// per-tile shuffle reductions, no post-softmax barrier (Ps is per-wave;
// DS ops are wave-in-order). Row sums reduced ONCE at the end.
// ===========================================================================
__global__ __launch_bounds__(256) void attn_mfma(const ushort* __restrict__ qkv,
                                                 float* __restrict__ attn_s) {
    const int p0 = blockIdx.x * 64;
    const int bh = blockIdx.y;
    const int b  = bh / H_, h = bh % H_;
    const int tid  = threadIdx.x;
    const int lane = tid & 63;
    const int wv   = tid >> 6;
    const int quad = lane >> 4;
    const int col  = lane & 15;

    __shared__ __align__(16) ushort Qs[64][72];
    __shared__ __align__(16) ushort Ks[64][72];
    __shared__ __align__(16) ushort Vs[64][72];      // [dim][key] transposed
    __shared__ __align__(16) ushort Ps[4][16][72];

    const size_t hs = (size_t)P_ * HD_;
    const ushort* qg = qkv + ((size_t)(0 * B_ + b) * H_ + h) * hs + (size_t)p0 * HD_;
    const ushort* kg = qkv + ((size_t)(1 * B_ + b) * H_ + h) * hs;
    const ushort* vg = qkv + ((size_t)(2 * B_ + b) * H_ + h) * hs;

    // Stage Q (64x64 bf16)
#pragma unroll
    for (int i = 0; i < 2; i++) {
        int e = tid + i * 256;
        int r = e >> 3, c8 = e & 7;
        *(uint4*)&Qs[r][c8 * 8] = *(const uint4*)(qg + (size_t)r * HD_ + c8 * 8);
    }
    __syncthreads();
    short8 aq0 = *(const short8*)&Qs[wv * 16 + col][0 * 32 + quad * 8];
    short8 aq1 = *(const short8*)&Qs[wv * 16 + col][1 * 32 + quad * 8];

    float lrow[4] = {0.f, 0.f, 0.f, 0.f};   // per-lane partial row sums
    f32x4 oacc[4];
#pragma unroll
    for (int nt = 0; nt < 4; nt++) oacc[nt] = (f32x4){0.f, 0.f, 0.f, 0.f};

    const int kr = tid >> 3, kc8 = tid & 7;
    const int vd = tid & 63,  vkh = tid >> 6;

    uint4  kpre[2];
    ushort vpre[16];
    auto load_tile = [&](int kt) {
        const ushort* kg_t = kg + (size_t)kt * 64 * HD_;
        const ushort* vg_t = vg + (size_t)kt * 64 * HD_;
        kpre[0] = *(const uint4*)(kg_t + (size_t)kr * HD_ + kc8 * 8);
        kpre[1] = *(const uint4*)(kg_t + (size_t)(kr + 32) * HD_ + kc8 * 8);
#pragma unroll
        for (int j = 0; j < 16; j++)
            vpre[j] = vg_t[(size_t)(vkh * 16 + j) * HD_ + vd];
    };

    load_tile(0);
    const int NT = P_ / 64;
    for (int kt = 0; kt < NT; kt++) {
        __syncthreads();
        *(uint4*)&Ks[kr][kc8 * 8]      = kpre[0];
        *(uint4*)&Ks[kr + 32][kc8 * 8] = kpre[1];
        *(short8*)&Vs[vd][vkh * 16]     = *(short8*)&vpre[0];
        *(short8*)&Vs[vd][vkh * 16 + 8] = *(short8*)&vpre[8];
        __syncthreads();
        if (kt + 1 < NT) load_tile(kt + 1);

        // S = Q @ K^T
        f32x4 s[4];
#pragma unroll
        for (int nt = 0; nt < 4; nt++) {
            s[nt] = (f32x4){0.f, 0.f, 0.f, 0.f};
            short8 b0 = *(const short8*)&Ks[nt * 16 + col][0 * 32 + quad * 8];
            short8 b1 = *(const short8*)&Ks[nt * 16 + col][1 * 32 + quad * 8];
            s[nt] = __builtin_amdgcn_mfma_f32_16x16x32_bf16(aq0, b0, s[nt], 0, 0, 0);
            s[nt] = __builtin_amdgcn_mfma_f32_16x16x32_bf16(aq1, b1, s[nt], 0, 0, 0);
        }

        // Unnormalized clamped softmax: p = exp(min(s,60)); accumulate row sums.
#pragma unroll
        for (int r = 0; r < 4; r++) {
#pragma unroll
            for (int nt = 0; nt < 4; nt++) {
                float p = __expf(fminf(s[nt][r], 60.f));
                lrow[r] += p;
                Ps[wv][quad * 4 + r][nt * 16 + col] = f2bf(p);
            }
        }
        // No barrier: Ps is per-wave, DS ops complete in order within a wave.

        // O += P @ V
#pragma unroll
        for (int nt = 0; nt < 4; nt++) {
#pragma unroll
            for (int ks2 = 0; ks2 < 2; ks2++) {
                short8 a   = *(const short8*)&Ps[wv][col][ks2 * 32 + quad * 8];
                short8 bfr = *(const short8*)&Vs[nt * 16 + col][ks2 * 32 + quad * 8];
                oacc[nt] = __builtin_amdgcn_mfma_f32_16x16x32_bf16(a, bfr, oacc[nt], 0, 0, 0);
            }
        }
    }

    // Final row-sum reduction: row quad*4+r lives in the 16 lanes of this quad
    // (xor over col bits stays within the quad).
#pragma unroll
    for (int r = 0; r < 4; r++) {
#pragma unroll
        for (int off = 1; off < 16; off <<= 1) lrow[r] += __shfl_xor(lrow[r], off, 64);
    }

#pragma unroll
    for (int r = 0; r < 4; r++) {
        float invl = 1.0f / lrow[r];
        int q = p0 + wv * 16 + quad * 4 + r;
        float* dst = attn_s + (size_t)(b * P_ + q) * D_ + h * HD_;
#pragma unroll
        for (int nt = 0; nt < 4; nt++) dst[nt * 16 + col] = oacc[nt][r] * invl;
    }
}

// ===========================================================================
// Kernel 3: LayerNorm over D=768. fp32 in (d_out scratch), bf16 out (ln_buf).
// ===========================================================================
__global__ __launch_bounds__(256) void ln_o(const float* __restrict__ a,
                                            ushort* __restrict__ lnb,
                                            const float* __restrict__ osc,
                                            const float* __restrict__ ob) {
    __shared__ float red[4];
    __shared__ float red2[4];
    const int row = blockIdx.x;
    const int tid = threadIdx.x;
    const size_t base = (size_t)row * D_;

    float v0 = a[base + tid];
    float v1 = a[base + tid + 256];
    float v2 = a[base + tid + 512];
    float s = v0 + v1 + v2;
#pragma unroll
    for (int o = 32; o > 0; o >>= 1) s += __shfl_xor(s, o, 64);
    if ((tid & 63) == 0) red[tid >> 6] = s;
    __syncthreads();
    float mean = (red[0] + red[1] + red[2] + red[3]) * (1.0f / 768.0f);
    float d0 = v0 - mean, d1 = v1 - mean, d2 = v2 - mean;
    float sq = d0 * d0 + d1 * d1 + d2 * d2;
#pragma unroll
    for (int o = 32; o > 0; o >>= 1) sq += __shfl_xor(sq, o, 64);
    if ((tid & 63) == 0) red2[tid >> 6] = sq;
    __syncthreads();
    float var = (red2[0] + red2[1] + red2[2] + red2[3]) * (1.0f / 768.0f);
    float inv = rsqrtf(var + 1e-6f);
    lnb[base + tid]       = f2bf(d0 * inv * osc[tid]       + ob[tid]);
    lnb[base + tid + 256] = f2bf(d1 * inv * osc[tid + 256] + ob[tid + 256]);
    lnb[base + tid + 512] = f2bf(d2 * inv * osc[tid + 512] + ob[tid + 512]);
}

// ===========================================================================
// Kernel 4: out = ln_buf(bf16) @ W_out + b_out, fp32 output. (unchanged R7)
// ===========================================================================
__global__ __launch_bounds__(256) void gemm_out_mfma(
        const ushort* __restrict__ a, const float* __restrict__ w,
        const float* __restrict__ bias, float* __restrict__ out) {
    __shared__ __align__(16) ushort As[128][40];
    __shared__ __align__(16) ushort Bs[128][40];

    const int tid  = threadIdx.x;
    const int lane = tid & 63;
    const int wv   = tid >> 6;
    const int quad = lane >> 4;
    const int col  = lane & 15;
    const int wr   = (wv >> 1) * 64;
    const int wc   = (wv & 1) * 64;
    const int rowBase = blockIdx.y * 128;
    const int colBase = blockIdx.x * 128;

    const int nB    = tid & 127;
    const int khalf = tid >> 7;
    const int am    = tid >> 2, ac8 = tid & 3;

    uint4 apre[2];
    float bpre[16];
    auto load_tile = [&](int kt) {
        const int k0 = kt * 32;
        apre[0] = *(const uint4*)(a + (size_t)(rowBase + am) * D_ + k0 + ac8 * 8);
        apre[1] = *(const uint4*)(a + (size_t)(rowBase + am + 64) * D_ + k0 + ac8 * 8);
#pragma unroll
        for (int j = 0; j < 16; j++)
            bpre[j] = w[(size_t)(k0 + khalf * 16 + j) * D_ + colBase + nB];
    };

    f32x4 acc[4][4];
#pragma unroll
    for (int i = 0; i < 4; i++)
#pragma unroll
        for (int j = 0; j < 4; j++) acc[i][j] = (f32x4){0.f, 0.f, 0.f, 0.f};

    load_tile(0);
    const int NT = D_ / 32;
    for (int kt = 0; kt < NT; kt++) {
        __syncthreads();
        *(uint4*)&As[am][ac8 * 8]      = apre[0];
        *(uint4*)&As[am + 64][ac8 * 8] = apre[1];
        {
            ushort us[16];
#pragma unroll
            for (int j = 0; j < 16; j++) us[j] = f2bf(bpre[j]);
            *(short8*)&Bs[nB][khalf * 16]     = *(short8*)&us[0];
            *(short8*)&Bs[nB][khalf * 16 + 8] = *(short8*)&us[8];
        }
        __syncthreads();
        if (kt + 1 < NT) load_tile(kt + 1);

        short8 af[4], bf[4];
#pragma unroll
        for (int mt = 0; mt < 4; mt++) af[mt] = *(const short8*)&As[wr + mt * 16 + col][quad * 8];
#pragma unroll
        for (int nt = 0; nt < 4; nt++) bf[nt] = *(const short8*)&Bs[wc + nt * 16 + col][quad * 8];
#pragma unroll
        for (int mt = 0; mt < 4; mt++)
#pragma unroll
            for (int nt = 0; nt < 4; nt++)
                acc[mt][nt] = __builtin_amdgcn_mfma_f32_16x16x32_bf16(af[mt], bf[nt], acc[mt][nt], 0, 0, 0);
    }

    float b4[4];
#pragma unroll
    for (int nt = 0; nt < 4; nt++) b4[nt] = bias[colBase + wc + nt * 16 + col];
#pragma unroll
    for (int mt = 0; mt < 4; mt++) {
#pragma unroll
        for (int r = 0; r < 4; r++) {
            int m = rowBase + wr + mt * 16 + quad * 4 + r;
            float* dst = out + (size_t)m * D_ + colBase + wc;
#pragma unroll
            for (int nt = 0; nt < 4; nt++)
                dst[nt * 16 + col] = acc[mt][nt][r] + b4[nt];
        }
    }
}

// ---------------------------------------------------------------------------
extern "C" void kernel_launch(void* const* d_in, const int* in_sizes, int n_in,
                              void* d_out, int out_size, void* d_ws, size_t ws_size,
                              hipStream_t stream) {
    const float* x    = (const float*)d_in[0];
    const float* Wqkv = (const float*)d_in[1];
    const float* qs   = (const float*)d_in[2];
    const float* qb   = (const float*)d_in[3];
    const float* ks   = (const float*)d_in[4];
    const float* kb   = (const float*)d_in[5];
    const float* osc  = (const float*)d_in[6];
    const float* ob   = (const float*)d_in[7];
    const float* Wout = (const float*)d_in[8];
    const float* bout = (const float*)d_in[9];
    float* out = (float*)d_out;

    ushort* qkv    = (ushort*)d_ws;   // [3][B][H][P][hd] bf16, 18.9 MB
    float*  attn_s = out;             // d_out doubles as attention-output scratch
    ushort* ln_buf = qkv;             // overlays dead q-region after attn

    gemm_qkv_mfma<<<dim3(N1_ / 128, M_ / 128), 256, 0, stream>>>(x, Wqkv, qs, qb, ks, kb, qkv);
    attn_mfma<<<dim3(P_ / 64, B_ * H_), 256, 0, stream>>>(qkv, attn_s);
    ln_o<<<dim3(M_), 256, 0, stream>>>(attn_s, ln_buf, osc, ob);
    gemm_out_mfma<<<dim3(D_ / 128, M_ / 128), 256, 0, stream>>>(ln_buf, Wout, bout, out);
}